// Round 5
// baseline (12335.522 us; speedup 1.0000x reference)
//
#include <hip/hip_runtime.h>
#include <math.h>

namespace {
constexpr int L_ = 4, H_ = 4, D_ = 128, DFF_ = 512, T_ = 64, B_ = 1024;
constexpr int S_ = 4, BOS_ = 4, DH_ = 32;
constexpr int NBLK = B_;              // 1 batch element per block
constexpr int NTH = 256;              // threads per block (4 waves)

// workspace: KV cache only (exactly 256 MiB)
constexpr size_t KC_BLK = (size_t)L_ * T_ * D_;   // 32768 floats per block
constexpr size_t KC_OFF = 0;
constexpr size_t VC_OFF = KC_OFF + (size_t)NBLK * KC_BLK;
}

__device__ __forceinline__ float4 ld4(const float* p) {
  return *reinterpret_cast<const float4*>(p);
}

__device__ __forceinline__ float gelu_exact(float v) {
  return 0.5f * v * (1.0f + erff(v * 0.70710678118654752440f));
}

__global__ __launch_bounds__(NTH) void decode_kernel(
    const float* __restrict__ gumbel, const float* __restrict__ state_emb,
    const float* __restrict__ pos_emb,
    const float* __restrict__ ln1w, const float* __restrict__ ln1b,
    const float* __restrict__ wqkv, const float* __restrict__ bqkv,
    const float* __restrict__ wo, const float* __restrict__ bo,
    const float* __restrict__ ln2w, const float* __restrict__ ln2b,
    const float* __restrict__ w1, const float* __restrict__ b1,
    const float* __restrict__ w2, const float* __restrict__ b2,
    const float* __restrict__ fnw, const float* __restrict__ fnb,
    const float* __restrict__ headw, const float* __restrict__ headb,
    const int* __restrict__ nalpha, const int* __restrict__ nbeta,
    float* __restrict__ ws, float* __restrict__ out) {
  const int tid = threadIdx.x;
  const int blk = blockIdx.x;
  const int lane = tid & 63;
  const int w = tid >> 6;            // wave 0..3

  // GEMV-128 mapping: 64 output-groups x 4 k-slices
  const int og = tid >> 2;           // 0..63
  const int k4 = tid & 3;            // 0..3
  // GEMV-512 (FFN2) mapping: 32 output-groups x 8 k-slices
  const int og8 = tid >> 3;          // 0..31
  const int k8 = tid & 7;            // 0..7
  // PV mapping: wave w = head; tg = t-group, c8 = d-chunk within head
  const int tg = lane >> 3;          // 0..7
  const int c8 = lane & 7;           // 0..7
  const int chunk = w * 8 + c8;      // 0..31 (float4 chunk of d)

  float* Kc = ws + KC_OFF + (size_t)blk * KC_BLK;
  float* Vc = ws + VC_OFF + (size_t)blk * KC_BLK;

  __shared__ __align__(16) float xres[D_];
  __shared__ __align__(16) float xn[D_];
  __shared__ __align__(16) float qb[D_];      // q, later ctx
  __shared__ __align__(16) float hbuf[DFF_];
  __shared__ float sc[H_][T_];
  __shared__ float logits[S_];
  __shared__ int tok, arem, brem;
  __shared__ float lpsum;

  if (tid == 0) {
    tok = BOS_;
    arem = nalpha[0];
    brem = nbeta[0];
    lpsum = 0.f;
  }
  __syncthreads();

  for (int i = 0; i < T_; ++i) {
    // ---- embed
    if (tid < D_) xres[tid] = state_emb[tok * D_ + tid] + pos_emb[i * D_ + tid];
    __syncthreads();

    for (int l = 0; l < L_; ++l) {
      // ---- LN1 (wave 0; lane holds 2 values)
      if (w == 0) {
        float v0 = xres[lane], v1 = xres[lane + 64];
        float s = v0 + v1;
#pragma unroll
        for (int off = 32; off > 0; off >>= 1) s += __shfl_xor(s, off);
        float mu = s * (1.f / 128.f);
        float d0 = v0 - mu, d1 = v1 - mu;
        float s2 = d0 * d0 + d1 * d1;
#pragma unroll
        for (int off = 32; off > 0; off >>= 1) s2 += __shfl_xor(s2, off);
        float inv = 1.f / sqrtf(s2 * (1.f / 128.f) + 1e-5f);
        xn[lane] = d0 * inv * ln1w[l * D_ + lane] + ln1b[l * D_ + lane];
        xn[lane + 64] = d1 * inv * ln1w[l * D_ + lane + 64] + ln1b[l * D_ + lane + 64];
      }
      __syncthreads();

      // ---- QKV GEMV: 6 rows/og {og+64m}, k-slice shared x
      {
        const float* wb = wqkv + (size_t)l * 384 * D_;
        float a0 = 0.f, a1 = 0.f, a2 = 0.f, a3 = 0.f, a4 = 0.f, a5 = 0.f;
#pragma unroll
        for (int m = 0; m < 8; ++m) {
          const int f4 = k4 + 4 * m;          // float4 idx, bank-disjoint per k4
          const float4 x4 = ld4(&xn[4 * f4]);
          const float4 w0 = ld4(wb + (size_t)(og)*D_ + 4 * f4);
          const float4 w1v = ld4(wb + (size_t)(og + 64) * D_ + 4 * f4);
          const float4 w2v = ld4(wb + (size_t)(og + 128) * D_ + 4 * f4);
          const float4 w3v = ld4(wb + (size_t)(og + 192) * D_ + 4 * f4);
          const float4 w4v = ld4(wb + (size_t)(og + 256) * D_ + 4 * f4);
          const float4 w5v = ld4(wb + (size_t)(og + 320) * D_ + 4 * f4);
          a0 += w0.x * x4.x + w0.y * x4.y + w0.z * x4.z + w0.w * x4.w;
          a1 += w1v.x * x4.x + w1v.y * x4.y + w1v.z * x4.z + w1v.w * x4.w;
          a2 += w2v.x * x4.x + w2v.y * x4.y + w2v.z * x4.z + w2v.w * x4.w;
          a3 += w3v.x * x4.x + w3v.y * x4.y + w3v.z * x4.z + w3v.w * x4.w;
          a4 += w4v.x * x4.x + w4v.y * x4.y + w4v.z * x4.z + w4v.w * x4.w;
          a5 += w5v.x * x4.x + w5v.y * x4.y + w5v.z * x4.z + w5v.w * x4.w;
        }
        a0 += __shfl_xor(a0, 1); a0 += __shfl_xor(a0, 2);
        a1 += __shfl_xor(a1, 1); a1 += __shfl_xor(a1, 2);
        a2 += __shfl_xor(a2, 1); a2 += __shfl_xor(a2, 2);
        a3 += __shfl_xor(a3, 1); a3 += __shfl_xor(a3, 2);
        a4 += __shfl_xor(a4, 1); a4 += __shfl_xor(a4, 2);
        a5 += __shfl_xor(a5, 1); a5 += __shfl_xor(a5, 2);
        if (k4 == 0) {
          const float* bq = bqkv + l * 384;
          const size_t base = ((size_t)l * T_ + i) * D_;
          qb[og] = a0 + bq[og];
          qb[og + 64] = a1 + bq[og + 64];
          Kc[base + og] = a2 + bq[og + 128];
          Kc[base + og + 64] = a3 + bq[og + 192];
          Vc[base + og] = a4 + bq[og + 256];
          Vc[base + og + 64] = a5 + bq[og + 320];
        }
      }
      __syncthreads();

      // ---- scores + softmax: wave = head, lane = t
      {
        const int h = w, t = lane;
        float s0 = -INFINITY;
        if (t <= i) {
          const float4* q4 = reinterpret_cast<const float4*>(&qb[h * DH_]);
          const float4* kp = reinterpret_cast<const float4*>(
              Kc + ((size_t)l * T_ + t) * D_ + h * DH_);
          float a = 0.f;
#pragma unroll
          for (int k = 0; k < 8; ++k) {
            float4 qv = q4[k], kv = kp[k];
            a += qv.x * kv.x + qv.y * kv.y + qv.z * kv.z + qv.w * kv.w;
          }
          s0 = a * 0.17677669529663687f;
        }
        float m = s0;
#pragma unroll
        for (int off = 32; off > 0; off >>= 1) m = fmaxf(m, __shfl_xor(m, off));
        float p = expf(s0 - m);                 // 0 for t>i
        float sum = p;
#pragma unroll
        for (int off = 32; off > 0; off >>= 1) sum += __shfl_xor(sum, off);
        sc[h][t] = p / sum;
      }
      __syncthreads();

      // ---- PV: wave w = head, chunk = d-quarter slice; reduce over tg
      {
        float ax = 0.f, ay = 0.f, az = 0.f, aw = 0.f;
#pragma unroll
        for (int m = 0; m < 8; ++m) {
          const int t = tg + 8 * m;
          if (t <= i) {
            const float p = sc[w][t];
            const float4 v4 = ld4(Vc + ((size_t)l * T_ + t) * D_ + 4 * chunk);
            ax += p * v4.x; ay += p * v4.y; az += p * v4.z; aw += p * v4.w;
          }
        }
#pragma unroll
        for (int off = 8; off < 64; off <<= 1) {
          ax += __shfl_xor(ax, off);
          ay += __shfl_xor(ay, off);
          az += __shfl_xor(az, off);
          aw += __shfl_xor(aw, off);
        }
        if (tg == 0) {
          float4 r = {ax, ay, az, aw};
          *reinterpret_cast<float4*>(&qb[4 * chunk]) = r;
        }
      }
      __syncthreads();

      // ---- x += ctx @ wo.T + bo : 2 rows/og
      {
        const float* wb = wo + (size_t)l * D_ * D_;
        float a0 = 0.f, a1 = 0.f;
#pragma unroll
        for (int m = 0; m < 8; ++m) {
          const int f4 = k4 + 4 * m;
          const float4 x4 = ld4(&qb[4 * f4]);
          const float4 w0 = ld4(wb + (size_t)(og)*D_ + 4 * f4);
          const float4 w1v = ld4(wb + (size_t)(og + 64) * D_ + 4 * f4);
          a0 += w0.x * x4.x + w0.y * x4.y + w0.z * x4.z + w0.w * x4.w;
          a1 += w1v.x * x4.x + w1v.y * x4.y + w1v.z * x4.z + w1v.w * x4.w;
        }
        a0 += __shfl_xor(a0, 1); a0 += __shfl_xor(a0, 2);
        a1 += __shfl_xor(a1, 1); a1 += __shfl_xor(a1, 2);
        if (k4 == 0) {
          xres[og] += a0 + bo[l * D_ + og];
          xres[og + 64] += a1 + bo[l * D_ + og + 64];
        }
      }
      __syncthreads();

      // ---- LN2 (wave 0)
      if (w == 0) {
        float v0 = xres[lane], v1 = xres[lane + 64];
        float s = v0 + v1;
#pragma unroll
        for (int off = 32; off > 0; off >>= 1) s += __shfl_xor(s, off);
        float mu = s * (1.f / 128.f);
        float d0 = v0 - mu, d1 = v1 - mu;
        float s2 = d0 * d0 + d1 * d1;
#pragma unroll
        for (int off = 32; off > 0; off >>= 1) s2 += __shfl_xor(s2, off);
        float inv = 1.f / sqrtf(s2 * (1.f / 128.f) + 1e-5f);
        xn[lane] = d0 * inv * ln2w[l * D_ + lane] + ln2b[l * D_ + lane];
        xn[lane + 64] = d1 * inv * ln2w[l * D_ + lane + 64] + ln2b[l * D_ + lane + 64];
      }
      __syncthreads();

      // ---- FFN1 + GELU: 8 rows/og
      {
        const float* wb = w1 + (size_t)l * DFF_ * D_;
        float ac[8];
#pragma unroll
        for (int r = 0; r < 8; ++r) ac[r] = 0.f;
#pragma unroll
        for (int m = 0; m < 8; ++m) {
          const int f4 = k4 + 4 * m;
          const float4 x4 = ld4(&xn[4 * f4]);
#pragma unroll
          for (int r = 0; r < 8; ++r) {
            const float4 w4 = ld4(wb + (size_t)(og + 64 * r) * D_ + 4 * f4);
            ac[r] += w4.x * x4.x + w4.y * x4.y + w4.z * x4.z + w4.w * x4.w;
          }
        }
#pragma unroll
        for (int r = 0; r < 8; ++r) {
          ac[r] += __shfl_xor(ac[r], 1);
          ac[r] += __shfl_xor(ac[r], 2);
        }
        if (k4 == 0) {
#pragma unroll
          for (int r = 0; r < 8; ++r) {
            const int o = og + 64 * r;
            hbuf[o] = gelu_exact(ac[r] + b1[l * DFF_ + o]);
          }
        }
      }
      __syncthreads();

      // ---- FFN2: 4 rows/og8, 8-way k-slice over 512
      {
        const float* wb = w2 + (size_t)l * D_ * DFF_;
        float a0 = 0.f, a1 = 0.f, a2 = 0.f, a3 = 0.f;
#pragma unroll
        for (int m = 0; m < 16; ++m) {
          const int f4 = k8 + 8 * m;          // bank-disjoint per k8
          const float4 h4 = ld4(&hbuf[4 * f4]);
          const float4 w0 = ld4(wb + (size_t)(og8)*DFF_ + 4 * f4);
          const float4 w1v = ld4(wb + (size_t)(og8 + 32) * DFF_ + 4 * f4);
          const float4 w2v = ld4(wb + (size_t)(og8 + 64) * DFF_ + 4 * f4);
          const float4 w3v = ld4(wb + (size_t)(og8 + 96) * DFF_ + 4 * f4);
          a0 += w0.x * h4.x + w0.y * h4.y + w0.z * h4.z + w0.w * h4.w;
          a1 += w1v.x * h4.x + w1v.y * h4.y + w1v.z * h4.z + w1v.w * h4.w;
          a2 += w2v.x * h4.x + w2v.y * h4.y + w2v.z * h4.z + w2v.w * h4.w;
          a3 += w3v.x * h4.x + w3v.y * h4.y + w3v.z * h4.z + w3v.w * h4.w;
        }
#pragma unroll
        for (int off = 1; off < 8; off <<= 1) {
          a0 += __shfl_xor(a0, off);
          a1 += __shfl_xor(a1, off);
          a2 += __shfl_xor(a2, off);
          a3 += __shfl_xor(a3, off);
        }
        if (k8 == 0) {
          xres[og8] += a0 + b2[l * D_ + og8];
          xres[og8 + 32] += a1 + b2[l * D_ + og8 + 32];
          xres[og8 + 64] += a2 + b2[l * D_ + og8 + 64];
          xres[og8 + 96] += a3 + b2[l * D_ + og8 + 96];
        }
      }
      __syncthreads();
    }  // layers

    // ---- final LN (wave 0)
    if (w == 0) {
      float v0 = xres[lane], v1 = xres[lane + 64];
      float s = v0 + v1;
#pragma unroll
      for (int off = 32; off > 0; off >>= 1) s += __shfl_xor(s, off);
      float mu = s * (1.f / 128.f);
      float d0 = v0 - mu, d1 = v1 - mu;
      float s2 = d0 * d0 + d1 * d1;
#pragma unroll
      for (int off = 32; off > 0; off >>= 1) s2 += __shfl_xor(s2, off);
      float inv = 1.f / sqrtf(s2 * (1.f / 128.f) + 1e-5f);
      xn[lane] = d0 * inv * fnw[lane] + fnb[lane];
      xn[lane + 64] = d1 * inv * fnw[lane + 64] + fnb[lane + 64];
    }
    __syncthreads();

    // ---- head: 4 outputs x 32 lanes
    if (tid < 128) {
      const int s = tid >> 5, j = tid & 31;
      const float4 a = ld4(&xn[4 * j]);
      const float4 hw = ld4(headw + s * D_ + 4 * j);
      float acc = a.x * hw.x + a.y * hw.y + a.z * hw.z + a.w * hw.w;
#pragma unroll
      for (int off = 1; off < 32; off <<= 1) acc += __shfl_xor(acc, off, 32);
      if (j == 0) logits[s] = acc + headb[s];
    }
    __syncthreads();

    // ---- mask + log-softmax + gumbel-argmax (thread 0)
    if (tid == 0) {
      int a = arem, bb = brem;
      int oa = T_ - 1 - i;
      bool m[4];
      m[0] = (a <= oa) && (bb <= oa);
      m[1] = (bb > 0) && (a <= oa) && (bb - 1 <= oa);
      m[2] = (a > 0) && (a - 1 <= oa) && (bb <= oa);
      m[3] = (a > 0) && (bb > 0) && (a - 1 <= oa) && (bb - 1 <= oa);
      float mx = -INFINITY;
#pragma unroll
      for (int s = 0; s < 4; ++s)
        if (m[s]) mx = fmaxf(mx, logits[s]);
      float sum = 0.f;
      float lg[4];
#pragma unroll
      for (int s = 0; s < 4; ++s) {
        if (m[s]) {
          float z = logits[s] - mx;
          sum += expf(z);
          lg[s] = z;
        } else {
          lg[s] = -INFINITY;
        }
      }
      float lse = logf(sum);
      float best = -INFINITY;
      int bs = 0;
#pragma unroll
      for (int s = 0; s < 4; ++s) {
        float lp = lg[s] - lse;
        float y = lp + gumbel[(size_t)blk * T_ * S_ + (size_t)i * S_ + s];
        if (y > best) { best = y; bs = s; }
      }
      lpsum += lg[bs] - lse;
      out[(size_t)blk * T_ + i] = (float)bs;
      tok = bs;
      arem = a - (bs >> 1);
      brem = bb - (bs & 1);
    }
    __syncthreads();
  }  // steps

  if (tid == 0) out[(size_t)B_ * T_ + blk] = lpsum;
}

extern "C" void kernel_launch(void* const* d_in, const int* in_sizes, int n_in,
                              void* d_out, int out_size, void* d_ws, size_t ws_size,
                              hipStream_t stream) {
  const float* gumbel    = (const float*)d_in[0];
  const float* state_emb = (const float*)d_in[1];
  const float* pos_emb   = (const float*)d_in[2];
  const float* ln1w      = (const float*)d_in[3];
  const float* ln1b      = (const float*)d_in[4];
  const float* wqkv      = (const float*)d_in[5];
  const float* bqkv      = (const float*)d_in[6];
  const float* wo        = (const float*)d_in[7];
  const float* bo        = (const float*)d_in[8];
  const float* ln2w      = (const float*)d_in[9];
  const float* ln2b      = (const float*)d_in[10];
  const float* w1        = (const float*)d_in[11];
  const float* b1        = (const float*)d_in[12];
  const float* w2        = (const float*)d_in[13];
  const float* b2        = (const float*)d_in[14];
  const float* fnw       = (const float*)d_in[15];
  const float* fnb       = (const float*)d_in[16];
  const float* headw     = (const float*)d_in[17];
  const float* headb     = (const float*)d_in[18];
  const int* nalpha      = (const int*)d_in[19];
  const int* nbeta       = (const int*)d_in[20];
  float* ws = (float*)d_ws;
  float* out = (float*)d_out;

  decode_kernel<<<dim3(NBLK), dim3(NTH), 0, stream>>>(
      gumbel, state_emb, pos_emb, ln1w, ln1b, wqkv, bqkv, wo, bo, ln2w, ln2b,
      w1, b1, w2, b2, fnw, fnb, headw, headb, nalpha, nbeta, ws, out);
}

// Round 6
// 10764.694 us; speedup vs baseline: 1.1459x; 1.1459x over previous
//
#include <hip/hip_runtime.h>
#include <math.h>

namespace {
constexpr int L_ = 4, H_ = 4, D_ = 128, DFF_ = 512, T_ = 64, B_ = 1024;
constexpr int S_ = 4, BOS_ = 4, DH_ = 32;
constexpr int NB = 4;                 // batch elements per block (amortizes weight L2 traffic)
constexpr int NBLK = B_ / NB;         // 256 blocks = 1 per CU
constexpr int NTH = 1024;             // 16 waves per block

// workspace: KV cache only (exactly 256 MiB)
constexpr size_t KC_BLK = (size_t)L_ * NB * T_ * D_;
constexpr size_t KC_OFF = 0;
constexpr size_t VC_OFF = KC_OFF + (size_t)NBLK * KC_BLK;
}

__device__ __forceinline__ float4 ld4(const float* p) {
  return *reinterpret_cast<const float4*>(p);
}

__device__ __forceinline__ float gelu_exact(float v) {
  return 0.5f * v * (1.0f + erff(v * 0.70710678118654752440f));
}

#define SEL4(a, e) ((e) == 0 ? (a)[0] : (e) == 1 ? (a)[1] : (e) == 2 ? (a)[2] : (a)[3])

// one wave normalizes one 128-vector: lane holds src[lane], src[lane+64]
__device__ __forceinline__ void ln_wave(const float* __restrict__ src,
                                        float* __restrict__ dst,
                                        const float* __restrict__ w,
                                        const float* __restrict__ b, int lane) {
  float v0 = src[lane], v1 = src[lane + 64];
  float s = v0 + v1;
#pragma unroll
  for (int off = 32; off > 0; off >>= 1) s += __shfl_xor(s, off);
  float mu = s * (1.f / 128.f);
  float d0 = v0 - mu, d1 = v1 - mu;
  float s2 = d0 * d0 + d1 * d1;
#pragma unroll
  for (int off = 32; off > 0; off >>= 1) s2 += __shfl_xor(s2, off);
  float inv = 1.f / sqrtf(s2 * (1.f / 128.f) + 1e-5f);
  dst[lane] = d0 * inv * w[lane] + b[lane];
  dst[lane + 64] = d1 * inv * w[lane + 64] + b[lane + 64];
}

__global__ __launch_bounds__(NTH) void decode_kernel(
    const float* __restrict__ gumbel, const float* __restrict__ state_emb,
    const float* __restrict__ pos_emb,
    const float* __restrict__ ln1w, const float* __restrict__ ln1b,
    const float* __restrict__ wqkv, const float* __restrict__ bqkv,
    const float* __restrict__ wo, const float* __restrict__ bo,
    const float* __restrict__ ln2w, const float* __restrict__ ln2b,
    const float* __restrict__ w1, const float* __restrict__ b1,
    const float* __restrict__ w2, const float* __restrict__ b2,
    const float* __restrict__ fnw, const float* __restrict__ fnb,
    const float* __restrict__ headw, const float* __restrict__ headb,
    const int* __restrict__ nalpha, const int* __restrict__ nbeta,
    float* __restrict__ ws, float* __restrict__ out) {
  const int tid = threadIdx.x;
  const int blk = blockIdx.x;
  const int lane = tid & 63;
  const int w = tid >> 6;            // wave 0..15
  const int og = tid >> 3;           // 0..127 (output row)
  const int k8 = tid & 7;            // 0..7   (k-slice of 16 floats)

  float* Kc = ws + KC_OFF + (size_t)blk * KC_BLK;
  float* Vc = ws + VC_OFF + (size_t)blk * KC_BLK;

  __shared__ __align__(16) float xres[NB][D_];
  __shared__ __align__(16) float xn[NB][D_];
  __shared__ __align__(16) float qb[NB][D_];    // q, later ctx
  __shared__ __align__(16) float hbuf[NB][DFF_];
  __shared__ float logits[NB][S_];
  __shared__ int tok[NB];

  // sampler state lives in registers of threads 0..3
  int arem_r = 0, brem_r = 0;
  float lps_r = 0.f;
  if (tid < NB) {
    tok[tid] = BOS_;
    arem_r = nalpha[0];
    brem_r = nbeta[0];
  }
  __syncthreads();

  for (int i = 0; i < T_; ++i) {
    // ---- embed
    if (tid < 512) {
      const int e = tid >> 7, d = tid & 127;
      xres[e][d] = state_emb[tok[e] * D_ + d] + pos_emb[i * D_ + d];
    }
    __syncthreads();

    for (int l = 0; l < L_; ++l) {
      // ---- LN1: waves 0..3, wave = element
      if (w < NB) ln_wave(xres[w], xn[w], ln1w + l * D_, ln1b + l * D_, lane);
      __syncthreads();

      // ---- QKV: thread (og,k8) does rows og(q), og+128(k), og+256(v), k-slice 16
      {
        float aq[4] = {0.f, 0.f, 0.f, 0.f};
        float ak[4] = {0.f, 0.f, 0.f, 0.f};
        float av[4] = {0.f, 0.f, 0.f, 0.f};
        const float* wq = wqkv + ((size_t)l * 384 + og) * D_ + 16 * k8;
        const float* wk = wq + (size_t)128 * D_;
        const float* wv = wq + (size_t)256 * D_;
#pragma unroll
        for (int m = 0; m < 4; ++m) {
          const float4 q4 = ld4(wq + 4 * m);
          const float4 k4v = ld4(wk + 4 * m);
          const float4 v4 = ld4(wv + 4 * m);
#pragma unroll
          for (int e = 0; e < 4; ++e) {
            const float4 x4 = ld4(&xn[e][16 * k8 + 4 * m]);
            aq[e] += q4.x * x4.x + q4.y * x4.y + q4.z * x4.z + q4.w * x4.w;
            ak[e] += k4v.x * x4.x + k4v.y * x4.y + k4v.z * x4.z + k4v.w * x4.w;
            av[e] += v4.x * x4.x + v4.y * x4.y + v4.z * x4.z + v4.w * x4.w;
          }
        }
#pragma unroll
        for (int e = 0; e < 4; ++e) {
          aq[e] += __shfl_xor(aq[e], 1); aq[e] += __shfl_xor(aq[e], 2); aq[e] += __shfl_xor(aq[e], 4);
          ak[e] += __shfl_xor(ak[e], 1); ak[e] += __shfl_xor(ak[e], 2); ak[e] += __shfl_xor(ak[e], 4);
          av[e] += __shfl_xor(av[e], 1); av[e] += __shfl_xor(av[e], 2); av[e] += __shfl_xor(av[e], 4);
        }
        const size_t kvb = ((size_t)l * NB) * T_ * D_ + (size_t)i * D_ + og;
        if (k8 < 4) {
          const int e = k8;
          qb[e][og] = SEL4(aq, e) + bqkv[l * 384 + og];
          Vc[kvb + (size_t)e * T_ * D_] = SEL4(av, e) + bqkv[l * 384 + 256 + og];
        } else {
          const int e = k8 - 4;
          Kc[kvb + (size_t)e * T_ * D_] = SEL4(ak, e) + bqkv[l * 384 + 128 + og];
        }
      }
      __syncthreads();

      // ---- attention: wave = (e,h); scores + softmax + PV in one phase
      {
        const int e = w >> 2, h = w & 3;
        const int t = lane;
        float s0 = -INFINITY;
        if (t <= i) {
          const float4* q4 = reinterpret_cast<const float4*>(&qb[e][h * DH_]);
          const float* kp = Kc + (((size_t)l * NB + e) * T_ + t) * D_ + h * DH_;
          float a = 0.f;
#pragma unroll
          for (int k = 0; k < 8; ++k) {
            const float4 qv = q4[k];
            const float4 kv = ld4(kp + 4 * k);
            a += qv.x * kv.x + qv.y * kv.y + qv.z * kv.z + qv.w * kv.w;
          }
          s0 = a * 0.17677669529663687f;
        }
        float m = s0;
#pragma unroll
        for (int off = 32; off > 0; off >>= 1) m = fmaxf(m, __shfl_xor(m, off));
        float p = expf(s0 - m);                 // 0 for t>i
        float sum = p;
#pragma unroll
        for (int off = 32; off > 0; off >>= 1) sum += __shfl_xor(sum, off);
        p = p / sum;
        // PV: lane (tg,j): j = d within head, tg = t-half; P shared via shfl
        const int j = lane & 31, tg = lane >> 5;
        const float* vp = Vc + (((size_t)l * NB + e) * T_) * D_ + h * DH_ + j;
        float acc = 0.f;
        const int tend = (i < tg * 32 + 31) ? i : (tg * 32 + 31);
        for (int t2 = tg * 32; t2 <= tend; ++t2) {
          const float pt = __shfl(p, t2);
          acc += pt * vp[(size_t)t2 * D_];
        }
        acc += __shfl_xor(acc, 32);
        if (tg == 0) qb[e][h * DH_ + j] = acc;
      }
      __syncthreads();

      // ---- x += ctx @ wo.T + bo
      {
        float ac[4] = {0.f, 0.f, 0.f, 0.f};
        const float* wrow = wo + ((size_t)l * D_ + og) * D_ + 16 * k8;
#pragma unroll
        for (int m = 0; m < 4; ++m) {
          const float4 w4 = ld4(wrow + 4 * m);
#pragma unroll
          for (int e = 0; e < 4; ++e) {
            const float4 x4 = ld4(&qb[e][16 * k8 + 4 * m]);
            ac[e] += w4.x * x4.x + w4.y * x4.y + w4.z * x4.z + w4.w * x4.w;
          }
        }
#pragma unroll
        for (int e = 0; e < 4; ++e) {
          ac[e] += __shfl_xor(ac[e], 1); ac[e] += __shfl_xor(ac[e], 2); ac[e] += __shfl_xor(ac[e], 4);
        }
        if (k8 < 4) {
          const int e = k8;
          xres[e][og] += SEL4(ac, e) + bo[l * D_ + og];
        }
      }
      __syncthreads();

      // ---- LN2
      if (w < NB) ln_wave(xres[w], xn[w], ln2w + l * D_, ln2b + l * D_, lane);
      __syncthreads();

      // ---- FFN1 + GELU: thread (og,k8) does rows og+{0,128,256,384}
      {
        float ac[4][4];
#pragma unroll
        for (int r = 0; r < 4; ++r)
#pragma unroll
          for (int e = 0; e < 4; ++e) ac[r][e] = 0.f;
        const float* wb = w1 + ((size_t)l * DFF_ + og) * D_ + 16 * k8;
#pragma unroll
        for (int m = 0; m < 4; ++m) {
          float4 wr[4];
#pragma unroll
          for (int r = 0; r < 4; ++r) wr[r] = ld4(wb + (size_t)(128 * r) * D_ + 4 * m);
#pragma unroll
          for (int e = 0; e < 4; ++e) {
            const float4 x4 = ld4(&xn[e][16 * k8 + 4 * m]);
#pragma unroll
            for (int r = 0; r < 4; ++r) {
              ac[r][e] += wr[r].x * x4.x + wr[r].y * x4.y + wr[r].z * x4.z + wr[r].w * x4.w;
            }
          }
        }
#pragma unroll
        for (int r = 0; r < 4; ++r)
#pragma unroll
          for (int e = 0; e < 4; ++e) {
            ac[r][e] += __shfl_xor(ac[r][e], 1);
            ac[r][e] += __shfl_xor(ac[r][e], 2);
            ac[r][e] += __shfl_xor(ac[r][e], 4);
          }
        if (k8 < 4) {
          const int e = k8;
          hbuf[e][og] = gelu_exact(SEL4(ac[0], e) + b1[l * DFF_ + og]);
          hbuf[e][og + 128] = gelu_exact(SEL4(ac[1], e) + b1[l * DFF_ + og + 128]);
        } else {
          const int e = k8 - 4;
          hbuf[e][og + 256] = gelu_exact(SEL4(ac[2], e) + b1[l * DFF_ + og + 256]);
          hbuf[e][og + 384] = gelu_exact(SEL4(ac[3], e) + b1[l * DFF_ + og + 384]);
        }
      }
      __syncthreads();

      // ---- FFN2: thread (og,k8), k-slice 64 floats of 512
      {
        float ac[4] = {0.f, 0.f, 0.f, 0.f};
        const float* wrow = w2 + ((size_t)l * D_ + og) * DFF_ + 64 * k8;
#pragma unroll
        for (int m = 0; m < 16; ++m) {
          const float4 w4 = ld4(wrow + 4 * m);
#pragma unroll
          for (int e = 0; e < 4; ++e) {
            const float4 h4 = ld4(&hbuf[e][64 * k8 + 4 * m]);
            ac[e] += w4.x * h4.x + w4.y * h4.y + w4.z * h4.z + w4.w * h4.w;
          }
        }
#pragma unroll
        for (int e = 0; e < 4; ++e) {
          ac[e] += __shfl_xor(ac[e], 1); ac[e] += __shfl_xor(ac[e], 2); ac[e] += __shfl_xor(ac[e], 4);
        }
        if (k8 < 4) {
          const int e = k8;
          xres[e][og] += SEL4(ac, e) + b2[l * D_ + og];
        }
      }
      __syncthreads();
    }  // layers

    // ---- final LN
    if (w < NB) ln_wave(xres[w], xn[w], fnw, fnb, lane);
    __syncthreads();

    // ---- head: 512 threads: (e, s, j)
    if (tid < 512) {
      const int e = tid >> 7, rest = tid & 127, s = rest >> 5, j = rest & 31;
      const float4 a = ld4(&xn[e][4 * j]);
      const float4 hw = ld4(headw + s * D_ + 4 * j);
      float acc = a.x * hw.x + a.y * hw.y + a.z * hw.z + a.w * hw.w;
#pragma unroll
      for (int off = 1; off < 32; off <<= 1) acc += __shfl_xor(acc, off);
      if (j == 0) logits[e][s] = acc + headb[s];
    }
    __syncthreads();

    // ---- mask + log-softmax + gumbel-argmax (threads 0..3)
    if (tid < NB) {
      const int e = tid;
      const int b = blk * NB + e;
      const int a = arem_r, bb = brem_r;
      const int oa = T_ - 1 - i;
      bool m[4];
      m[0] = (a <= oa) && (bb <= oa);
      m[1] = (bb > 0) && (a <= oa) && (bb - 1 <= oa);
      m[2] = (a > 0) && (a - 1 <= oa) && (bb <= oa);
      m[3] = (a > 0) && (bb > 0) && (a - 1 <= oa) && (bb - 1 <= oa);
      float mx = -INFINITY;
#pragma unroll
      for (int s = 0; s < 4; ++s)
        if (m[s]) mx = fmaxf(mx, logits[e][s]);
      float sum = 0.f;
      float lg[4];
#pragma unroll
      for (int s = 0; s < 4; ++s) {
        if (m[s]) {
          const float z = logits[e][s] - mx;
          sum += expf(z);
          lg[s] = z;
        } else {
          lg[s] = -INFINITY;
        }
      }
      const float lse = logf(sum);
      float best = -INFINITY;
      int bs = 0;
#pragma unroll
      for (int s = 0; s < 4; ++s) {
        const float lp = lg[s] - lse;
        const float y = lp + gumbel[((size_t)b * T_ + i) * S_ + s];
        if (y > best) { best = y; bs = s; }
      }
      lps_r += SEL4(lg, bs) - lse;
      out[(size_t)b * T_ + i] = (float)bs;
      tok[e] = bs;
      arem_r = a - (bs >> 1);
      brem_r = bb - (bs & 1);
    }
    __syncthreads();
  }  // steps

  if (tid < NB) out[(size_t)B_ * T_ + blk * NB + tid] = lps_r;
}

extern "C" void kernel_launch(void* const* d_in, const int* in_sizes, int n_in,
                              void* d_out, int out_size, void* d_ws, size_t ws_size,
                              hipStream_t stream) {
  const float* gumbel    = (const float*)d_in[0];
  const float* state_emb = (const float*)d_in[1];
  const float* pos_emb   = (const float*)d_in[2];
  const float* ln1w      = (const float*)d_in[3];
  const float* ln1b      = (const float*)d_in[4];
  const float* wqkv      = (const float*)d_in[5];
  const float* bqkv      = (const float*)d_in[6];
  const float* wo        = (const float*)d_in[7];
  const float* bo        = (const float*)d_in[8];
  const float* ln2w      = (const float*)d_in[9];
  const float* ln2b      = (const float*)d_in[10];
  const float* w1        = (const float*)d_in[11];
  const float* b1        = (const float*)d_in[12];
  const float* w2        = (const float*)d_in[13];
  const float* b2        = (const float*)d_in[14];
  const float* fnw       = (const float*)d_in[15];
  const float* fnb       = (const float*)d_in[16];
  const float* headw     = (const float*)d_in[17];
  const float* headb     = (const float*)d_in[18];
  const int* nalpha      = (const int*)d_in[19];
  const int* nbeta       = (const int*)d_in[20];
  float* ws = (float*)d_ws;
  float* out = (float*)d_out;

  decode_kernel<<<dim3(NBLK), dim3(NTH), 0, stream>>>(
      gumbel, state_emb, pos_emb, ln1w, ln1b, wqkv, bqkv, wo, bo, ln2w, ln2b,
      w1, b1, w2, b2, fnw, fnb, headw, headb, nalpha, nbeta, ws, out);
}

// Round 7
// 9241.025 us; speedup vs baseline: 1.3349x; 1.1649x over previous
//
#include <hip/hip_runtime.h>
#include <math.h>

namespace {
constexpr int L_ = 4, H_ = 4, D_ = 128, DFF_ = 512, T_ = 64, B_ = 1024;
constexpr int S_ = 4, BOS_ = 4, DH_ = 32;
constexpr int NB = 4;                 // batch elements per block (amortizes weight L2 traffic)
constexpr int NBLK = B_ / NB;         // 256 blocks = 1 per CU
constexpr int NTH = 1024;             // 16 waves per block

// workspace: KV cache only (exactly 256 MiB)
constexpr size_t KC_BLK = (size_t)L_ * NB * T_ * D_;
constexpr size_t KC_OFF = 0;
constexpr size_t VC_OFF = KC_OFF + (size_t)NBLK * KC_BLK;
}

__device__ __forceinline__ float4 ld4(const float* p) {
  return *reinterpret_cast<const float4*>(p);
}

__device__ __forceinline__ float gelu_exact(float v) {
  return 0.5f * v * (1.0f + erff(v * 0.70710678118654752440f));
}

#define SEL4(a, e) ((e) == 0 ? (a)[0] : (e) == 1 ? (a)[1] : (e) == 2 ? (a)[2] : (a)[3])

// one wave normalizes one 128-vector: lane holds src[lane], src[lane+64]
__device__ __forceinline__ void ln_wave(const float* __restrict__ src,
                                        float* __restrict__ dst,
                                        const float* __restrict__ w,
                                        const float* __restrict__ b, int lane) {
  float v0 = src[lane], v1 = src[lane + 64];
  float s = v0 + v1;
#pragma unroll
  for (int off = 32; off > 0; off >>= 1) s += __shfl_xor(s, off);
  float mu = s * (1.f / 128.f);
  float d0 = v0 - mu, d1 = v1 - mu;
  float s2 = d0 * d0 + d1 * d1;
#pragma unroll
  for (int off = 32; off > 0; off >>= 1) s2 += __shfl_xor(s2, off);
  float inv = 1.f / sqrtf(s2 * (1.f / 128.f) + 1e-5f);
  dst[lane] = d0 * inv * w[lane] + b[lane];
  dst[lane + 64] = d1 * inv * w[lane + 64] + b[lane + 64];
}

__global__ __launch_bounds__(NTH) void decode_kernel(
    const float* __restrict__ gumbel, const float* __restrict__ state_emb,
    const float* __restrict__ pos_emb,
    const float* __restrict__ ln1w, const float* __restrict__ ln1b,
    const float* __restrict__ wqkv, const float* __restrict__ bqkv,
    const float* __restrict__ wo, const float* __restrict__ bo,
    const float* __restrict__ ln2w, const float* __restrict__ ln2b,
    const float* __restrict__ w1, const float* __restrict__ b1,
    const float* __restrict__ w2, const float* __restrict__ b2,
    const float* __restrict__ fnw, const float* __restrict__ fnb,
    const float* __restrict__ headw, const float* __restrict__ headb,
    const int* __restrict__ nalpha, const int* __restrict__ nbeta,
    float* __restrict__ ws, float* __restrict__ out) {
  const int tid = threadIdx.x;
  const int blk = blockIdx.x;
  const int lane = tid & 63;
  const int w = tid >> 6;            // wave 0..15
  const int og = tid >> 3;           // 0..127 (output row)
  const int k8 = tid & 7;            // 0..7   (interleaved k-slice)

  float* Kc = ws + KC_OFF + (size_t)blk * KC_BLK;
  float* Vc = ws + VC_OFF + (size_t)blk * KC_BLK;

  __shared__ __align__(16) float xres[NB][D_];
  __shared__ __align__(16) float xn[NB][D_];
  __shared__ __align__(16) float qb[NB][D_];    // q, later ctx
  __shared__ __align__(16) float hbuf[NB][DFF_];
  __shared__ float sc[NB][H_][T_];              // softmax probs (0 for t>i)
  __shared__ float logits[NB][S_];
  __shared__ int tok[NB];

  // sampler state lives in registers of threads 0..3
  int arem_r = 0, brem_r = 0;
  float lps_r = 0.f;
  if (tid < NB) {
    tok[tid] = BOS_;
    arem_r = nalpha[0];
    brem_r = nbeta[0];
  }
  __syncthreads();

  for (int i = 0; i < T_; ++i) {
    // ---- embed
    if (tid < 512) {
      const int e = tid >> 7, d = tid & 127;
      xres[e][d] = state_emb[tok[e] * D_ + d] + pos_emb[i * D_ + d];
    }
    __syncthreads();

    for (int l = 0; l < L_; ++l) {
      // ---- LN1: waves 0..3, wave = element
      if (w < NB) ln_wave(xres[w], xn[w], ln1w + l * D_, ln1b + l * D_, lane);
      __syncthreads();

      // ---- QKV: thread (og,k8): rows og(q), og+128(k), og+256(v); f4 = k8+8m
      {
        float aq[4] = {0.f, 0.f, 0.f, 0.f};
        float ak[4] = {0.f, 0.f, 0.f, 0.f};
        float av[4] = {0.f, 0.f, 0.f, 0.f};
        const float* wq = wqkv + ((size_t)l * 384 + og) * D_;
        const float* wk = wq + (size_t)128 * D_;
        const float* wv = wq + (size_t)256 * D_;
#pragma unroll
        for (int m = 0; m < 4; ++m) {
          const int f4 = k8 + 8 * m;
          const float4 q4 = ld4(wq + 4 * f4);
          const float4 k4v = ld4(wk + 4 * f4);
          const float4 v4 = ld4(wv + 4 * f4);
#pragma unroll
          for (int e = 0; e < 4; ++e) {
            const float4 x4 = ld4(&xn[e][4 * f4]);
            aq[e] += q4.x * x4.x + q4.y * x4.y + q4.z * x4.z + q4.w * x4.w;
            ak[e] += k4v.x * x4.x + k4v.y * x4.y + k4v.z * x4.z + k4v.w * x4.w;
            av[e] += v4.x * x4.x + v4.y * x4.y + v4.z * x4.z + v4.w * x4.w;
          }
        }
#pragma unroll
        for (int e = 0; e < 4; ++e) {
          aq[e] += __shfl_xor(aq[e], 1); aq[e] += __shfl_xor(aq[e], 2); aq[e] += __shfl_xor(aq[e], 4);
          ak[e] += __shfl_xor(ak[e], 1); ak[e] += __shfl_xor(ak[e], 2); ak[e] += __shfl_xor(ak[e], 4);
          av[e] += __shfl_xor(av[e], 1); av[e] += __shfl_xor(av[e], 2); av[e] += __shfl_xor(av[e], 4);
        }
        const size_t kvb = ((size_t)l * NB) * T_ * D_ + (size_t)i * D_ + og;
        if (k8 < 4) {
          const int e = k8;
          qb[e][og] = SEL4(aq, e) + bqkv[l * 384 + og];
          Vc[kvb + (size_t)e * T_ * D_] = SEL4(av, e) + bqkv[l * 384 + 256 + og];
        } else {
          const int e = k8 - 4;
          Kc[kvb + (size_t)e * T_ * D_] = SEL4(ak, e) + bqkv[l * 384 + 128 + og];
        }
      }
      __syncthreads();

      // ---- attention: wave = (e,h); scores + softmax + PV, no internal barrier
      {
        const int e = w >> 2, h = w & 3;
        // scores: lane = t
        const int t = lane;
        float s0 = -INFINITY;
        {
          const float4* q4 = reinterpret_cast<const float4*>(&qb[e][h * DH_]);
          const float* kp = Kc + (((size_t)l * NB + e) * T_ + t) * D_ + h * DH_;
          float a = 0.f;
#pragma unroll
          for (int k = 0; k < 8; ++k) {
            const float4 qv = q4[k];
            const float4 kv = ld4(kp + 4 * k);
            a += qv.x * kv.x + qv.y * kv.y + qv.z * kv.z + qv.w * kv.w;
          }
          if (t <= i) s0 = a * 0.17677669529663687f;
        }
        float mx = s0;
#pragma unroll
        for (int off = 32; off > 0; off >>= 1) mx = fmaxf(mx, __shfl_xor(mx, off));
        float p = expf(s0 - mx);                 // 0 for t>i
        float sum = p;
#pragma unroll
        for (int off = 32; off > 0; off >>= 1) sum += __shfl_xor(sum, off);
        sc[e][h][t] = p / sum;                   // full 64 entries defined

        // PV: lane = (thalf, j); 32 static iterations, sc=0 masks t>i
        const int j = lane & 31, thalf = lane >> 5;
        const float* vp = Vc + (((size_t)l * NB + e) * T_ + thalf * 32) * D_ + h * DH_ + j;
        const float* pp = &sc[e][h][thalf * 32];
        float acc = 0.f;
#pragma unroll
        for (int m2 = 0; m2 < 32; ++m2) {
          acc += pp[m2] * vp[(size_t)m2 * D_];
        }
        acc += __shfl_xor(acc, 32);
        if (thalf == 0) qb[e][h * DH_ + j] = acc;
      }
      __syncthreads();

      // ---- x += ctx @ wo.T + bo
      {
        float ac[4] = {0.f, 0.f, 0.f, 0.f};
        const float* wrow = wo + ((size_t)l * D_ + og) * D_;
#pragma unroll
        for (int m = 0; m < 4; ++m) {
          const int f4 = k8 + 8 * m;
          const float4 w4 = ld4(wrow + 4 * f4);
#pragma unroll
          for (int e = 0; e < 4; ++e) {
            const float4 x4 = ld4(&qb[e][4 * f4]);
            ac[e] += w4.x * x4.x + w4.y * x4.y + w4.z * x4.z + w4.w * x4.w;
          }
        }
#pragma unroll
        for (int e = 0; e < 4; ++e) {
          ac[e] += __shfl_xor(ac[e], 1); ac[e] += __shfl_xor(ac[e], 2); ac[e] += __shfl_xor(ac[e], 4);
        }
        if (k8 < 4) {
          const int e = k8;
          xres[e][og] += SEL4(ac, e) + bo[l * D_ + og];
        }
      }
      __syncthreads();

      // ---- LN2
      if (w < NB) ln_wave(xres[w], xn[w], ln2w + l * D_, ln2b + l * D_, lane);
      __syncthreads();

      // ---- FFN1 + GELU: rows og+{0,128,256,384}
      {
        float ac[4][4];
#pragma unroll
        for (int r = 0; r < 4; ++r)
#pragma unroll
          for (int e = 0; e < 4; ++e) ac[r][e] = 0.f;
        const float* wb = w1 + ((size_t)l * DFF_ + og) * D_;
#pragma unroll
        for (int m = 0; m < 4; ++m) {
          const int f4 = k8 + 8 * m;
          float4 wr[4];
#pragma unroll
          for (int r = 0; r < 4; ++r) wr[r] = ld4(wb + (size_t)(128 * r) * D_ + 4 * f4);
#pragma unroll
          for (int e = 0; e < 4; ++e) {
            const float4 x4 = ld4(&xn[e][4 * f4]);
#pragma unroll
            for (int r = 0; r < 4; ++r) {
              ac[r][e] += wr[r].x * x4.x + wr[r].y * x4.y + wr[r].z * x4.z + wr[r].w * x4.w;
            }
          }
        }
#pragma unroll
        for (int r = 0; r < 4; ++r)
#pragma unroll
          for (int e = 0; e < 4; ++e) {
            ac[r][e] += __shfl_xor(ac[r][e], 1);
            ac[r][e] += __shfl_xor(ac[r][e], 2);
            ac[r][e] += __shfl_xor(ac[r][e], 4);
          }
        if (k8 < 4) {
          const int e = k8;
          hbuf[e][og] = gelu_exact(SEL4(ac[0], e) + b1[l * DFF_ + og]);
          hbuf[e][og + 128] = gelu_exact(SEL4(ac[1], e) + b1[l * DFF_ + og + 128]);
        } else {
          const int e = k8 - 4;
          hbuf[e][og + 256] = gelu_exact(SEL4(ac[2], e) + b1[l * DFF_ + og + 256]);
          hbuf[e][og + 384] = gelu_exact(SEL4(ac[3], e) + b1[l * DFF_ + og + 384]);
        }
      }
      __syncthreads();

      // ---- FFN2: thread (og,k8), f4 = k8+8m over 128 float4s
      {
        float ac[4] = {0.f, 0.f, 0.f, 0.f};
        const float* wrow = w2 + ((size_t)l * D_ + og) * DFF_;
#pragma unroll
        for (int m = 0; m < 16; ++m) {
          const int f4 = k8 + 8 * m;
          const float4 w4 = ld4(wrow + 4 * f4);
#pragma unroll
          for (int e = 0; e < 4; ++e) {
            const float4 h4 = ld4(&hbuf[e][4 * f4]);
            ac[e] += w4.x * h4.x + w4.y * h4.y + w4.z * h4.z + w4.w * h4.w;
          }
        }
#pragma unroll
        for (int e = 0; e < 4; ++e) {
          ac[e] += __shfl_xor(ac[e], 1); ac[e] += __shfl_xor(ac[e], 2); ac[e] += __shfl_xor(ac[e], 4);
        }
        if (k8 < 4) {
          const int e = k8;
          xres[e][og] += SEL4(ac, e) + b2[l * D_ + og];
        }
      }
      __syncthreads();
    }  // layers

    // ---- final LN
    if (w < NB) ln_wave(xres[w], xn[w], fnw, fnb, lane);
    __syncthreads();

    // ---- head: 512 threads: (e, s, j)
    if (tid < 512) {
      const int e = tid >> 7, rest = tid & 127, s = rest >> 5, j = rest & 31;
      const float4 a = ld4(&xn[e][4 * j]);
      const float4 hw = ld4(headw + s * D_ + 4 * j);
      float acc = a.x * hw.x + a.y * hw.y + a.z * hw.z + a.w * hw.w;
#pragma unroll
      for (int off = 1; off < 32; off <<= 1) acc += __shfl_xor(acc, off);
      if (j == 0) logits[e][s] = acc + headb[s];
    }
    __syncthreads();

    // ---- mask + log-softmax + gumbel-argmax (threads 0..3)
    if (tid < NB) {
      const int e = tid;
      const int b = blk * NB + e;
      const int a = arem_r, bb = brem_r;
      const int oa = T_ - 1 - i;
      bool m[4];
      m[0] = (a <= oa) && (bb <= oa);
      m[1] = (bb > 0) && (a <= oa) && (bb - 1 <= oa);
      m[2] = (a > 0) && (a - 1 <= oa) && (bb <= oa);
      m[3] = (a > 0) && (bb > 0) && (a - 1 <= oa) && (bb - 1 <= oa);
      float mx = -INFINITY;
#pragma unroll
      for (int s = 0; s < 4; ++s)
        if (m[s]) mx = fmaxf(mx, logits[e][s]);
      float sum = 0.f;
      float lg[4];
#pragma unroll
      for (int s = 0; s < 4; ++s) {
        if (m[s]) {
          const float z = logits[e][s] - mx;
          sum += expf(z);
          lg[s] = z;
        } else {
          lg[s] = -INFINITY;
        }
      }
      const float lse = logf(sum);
      float best = -INFINITY;
      int bs = 0;
#pragma unroll
      for (int s = 0; s < 4; ++s) {
        const float lp = lg[s] - lse;
        const float y = lp + gumbel[((size_t)b * T_ + i) * S_ + s];
        if (y > best) { best = y; bs = s; }
      }
      lps_r += SEL4(lg, bs) - lse;
      out[(size_t)b * T_ + i] = (float)bs;
      tok[e] = bs;
      arem_r = a - (bs >> 1);
      brem_r = bb - (bs & 1);
    }
    __syncthreads();
  }  // steps

  if (tid < NB) out[(size_t)B_ * T_ + blk * NB + tid] = lps_r;
}

extern "C" void kernel_launch(void* const* d_in, const int* in_sizes, int n_in,
                              void* d_out, int out_size, void* d_ws, size_t ws_size,
                              hipStream_t stream) {
  const float* gumbel    = (const float*)d_in[0];
  const float* state_emb = (const float*)d_in[1];
  const float* pos_emb   = (const float*)d_in[2];
  const float* ln1w      = (const float*)d_in[3];
  const float* ln1b      = (const float*)d_in[4];
  const float* wqkv      = (const float*)d_in[5];
  const float* bqkv      = (const float*)d_in[6];
  const float* wo        = (const float*)d_in[7];
  const float* bo        = (const float*)d_in[8];
  const float* ln2w      = (const float*)d_in[9];
  const float* ln2b      = (const float*)d_in[10];
  const float* w1        = (const float*)d_in[11];
  const float* b1        = (const float*)d_in[12];
  const float* w2        = (const float*)d_in[13];
  const float* b2        = (const float*)d_in[14];
  const float* fnw       = (const float*)d_in[15];
  const float* fnb       = (const float*)d_in[16];
  const float* headw     = (const float*)d_in[17];
  const float* headb     = (const float*)d_in[18];
  const int* nalpha      = (const int*)d_in[19];
  const int* nbeta       = (const int*)d_in[20];
  float* ws = (float*)d_ws;
  float* out = (float*)d_out;

  decode_kernel<<<dim3(NBLK), dim3(NTH), 0, stream>>>(
      gumbel, state_emb, pos_emb, ln1w, ln1b, wqkv, bqkv, wo, bo, ln2w, ln2b,
      w1, b1, w2, b2, fnw, fnb, headw, headb, nalpha, nbeta, ws, out);
}

// Round 8
// 7981.262 us; speedup vs baseline: 1.5456x; 1.1578x over previous
//
#include <hip/hip_runtime.h>
#include <math.h>

namespace {
constexpr int L_ = 4, H_ = 4, D_ = 128, DFF_ = 512, T_ = 64, B_ = 1024;
constexpr int S_ = 4, BOS_ = 4, DH_ = 32;
constexpr int NB = 4;                 // batch elements per block (amortizes weight L2 traffic)
constexpr int NBLK = B_ / NB;         // 256 blocks = 1 per CU
constexpr int NTH = 1024;             // 16 waves per block

// workspace: KV cache only (exactly 256 MiB)
constexpr size_t KC_BLK = (size_t)L_ * NB * T_ * D_;
constexpr size_t KC_OFF = 0;
constexpr size_t VC_OFF = KC_OFF + (size_t)NBLK * KC_BLK;
}

__device__ __forceinline__ float4 ld4(const float* p) {
  return *reinterpret_cast<const float4*>(p);
}

__device__ __forceinline__ float gelu_exact(float v) {
  return 0.5f * v * (1.0f + erff(v * 0.70710678118654752440f));
}

#define SEL4(a, e) ((e) == 0 ? (a)[0] : (e) == 1 ? (a)[1] : (e) == 2 ? (a)[2] : (a)[3])

// accumulate one float4 k-slice into per-element accumulators
#define DOT4(accv, w4, xptr)                                              \
  {                                                                       \
    const float4 x4_ = ld4(xptr);                                         \
    accv += (w4).x * x4_.x + (w4).y * x4_.y + (w4).z * x4_.z + (w4).w * x4_.w; \
  }

// one wave normalizes one 128-vector: lane holds src[lane], src[lane+64]
__device__ __forceinline__ void ln_wave(const float* __restrict__ src,
                                        float* __restrict__ dst,
                                        const float* __restrict__ w,
                                        const float* __restrict__ b, int lane) {
  float v0 = src[lane], v1 = src[lane + 64];
  float s = v0 + v1;
#pragma unroll
  for (int off = 32; off > 0; off >>= 1) s += __shfl_xor(s, off);
  float mu = s * (1.f / 128.f);
  float d0 = v0 - mu, d1 = v1 - mu;
  float s2 = d0 * d0 + d1 * d1;
#pragma unroll
  for (int off = 32; off > 0; off >>= 1) s2 += __shfl_xor(s2, off);
  float inv = 1.f / sqrtf(s2 * (1.f / 128.f) + 1e-5f);
  dst[lane] = d0 * inv * w[lane] + b[lane];
  dst[lane + 64] = d1 * inv * w[lane + 64] + b[lane + 64];
}

__global__ __launch_bounds__(NTH) void decode_kernel(
    const float* __restrict__ gumbel, const float* __restrict__ state_emb,
    const float* __restrict__ pos_emb,
    const float* __restrict__ ln1w, const float* __restrict__ ln1b,
    const float* __restrict__ wqkv, const float* __restrict__ bqkv,
    const float* __restrict__ wo, const float* __restrict__ bo,
    const float* __restrict__ ln2w, const float* __restrict__ ln2b,
    const float* __restrict__ w1, const float* __restrict__ b1,
    const float* __restrict__ w2, const float* __restrict__ b2,
    const float* __restrict__ fnw, const float* __restrict__ fnb,
    const float* __restrict__ headw, const float* __restrict__ headb,
    const int* __restrict__ nalpha, const int* __restrict__ nbeta,
    float* __restrict__ ws, float* __restrict__ out) {
  const int tid = threadIdx.x;
  const int blk = blockIdx.x;
  const int lane = tid & 63;
  const int w = tid >> 6;            // wave 0..15
  const int og = tid >> 3;           // 0..127 (output row)
  const int k8 = tid & 7;            // 0..7   (interleaved k-slice)

  float* Kc = ws + KC_OFF + (size_t)blk * KC_BLK;
  float* Vc = ws + VC_OFF + (size_t)blk * KC_BLK;

  __shared__ __align__(16) float xres[NB][D_];
  __shared__ __align__(16) float xn[NB][D_];
  __shared__ __align__(16) float qb[NB][D_];    // q, later ctx
  __shared__ __align__(16) float hbuf[NB][DFF_];
  __shared__ float sc[NB][H_][T_];              // softmax probs (0 for t>i)
  __shared__ float logits[NB][S_];
  __shared__ int tok[NB];

  int arem_r = 0, brem_r = 0;
  float lps_r = 0.f;
  if (tid < NB) {
    tok[tid] = BOS_;
    arem_r = nalpha[0];
    brem_r = nbeta[0];
  }
  __syncthreads();

  for (int i = 0; i < T_; ++i) {
    // ---- embed
    if (tid < 512) {
      const int e = tid >> 7, d = tid & 127;
      xres[e][d] = state_emb[tok[e] * D_ + d] + pos_emb[i * D_ + d];
    }
    __syncthreads();

    for (int l = 0; l < L_; ++l) {
      // ======== phase: LN1  (+ prefetch QKV weights m=0,1) ========
      const float* wqp = wqkv + ((size_t)l * 384 + og) * D_;
      const float* wkp = wqp + (size_t)128 * D_;
      const float* wvp = wqp + (size_t)256 * D_;
      const float4 pq0 = ld4(wqp + 4 * k8);
      const float4 pk0 = ld4(wkp + 4 * k8);
      const float4 pv0 = ld4(wvp + 4 * k8);
      const float4 pq1 = ld4(wqp + 4 * (k8 + 8));
      const float4 pk1 = ld4(wkp + 4 * (k8 + 8));
      const float4 pv1 = ld4(wvp + 4 * (k8 + 8));
      if (w < NB) ln_wave(xres[w], xn[w], ln1w + l * D_, ln1b + l * D_, lane);
      __syncthreads();

      // ======== phase: QKV ========
      {
        float aq[4] = {0.f, 0.f, 0.f, 0.f};
        float ak[4] = {0.f, 0.f, 0.f, 0.f};
        float av[4] = {0.f, 0.f, 0.f, 0.f};
#pragma unroll
        for (int e = 0; e < 4; ++e) {
          DOT4(aq[e], pq0, &xn[e][4 * k8]);
          DOT4(ak[e], pk0, &xn[e][4 * k8]);
          DOT4(av[e], pv0, &xn[e][4 * k8]);
          DOT4(aq[e], pq1, &xn[e][4 * (k8 + 8)]);
          DOT4(ak[e], pk1, &xn[e][4 * (k8 + 8)]);
          DOT4(av[e], pv1, &xn[e][4 * (k8 + 8)]);
        }
#pragma unroll
        for (int m = 2; m < 4; ++m) {
          const int f4 = k8 + 8 * m;
          const float4 q4 = ld4(wqp + 4 * f4);
          const float4 k4v = ld4(wkp + 4 * f4);
          const float4 v4 = ld4(wvp + 4 * f4);
#pragma unroll
          for (int e = 0; e < 4; ++e) {
            DOT4(aq[e], q4, &xn[e][4 * f4]);
            DOT4(ak[e], k4v, &xn[e][4 * f4]);
            DOT4(av[e], v4, &xn[e][4 * f4]);
          }
        }
#pragma unroll
        for (int e = 0; e < 4; ++e) {
          aq[e] += __shfl_xor(aq[e], 1); aq[e] += __shfl_xor(aq[e], 2); aq[e] += __shfl_xor(aq[e], 4);
          ak[e] += __shfl_xor(ak[e], 1); ak[e] += __shfl_xor(ak[e], 2); ak[e] += __shfl_xor(ak[e], 4);
          av[e] += __shfl_xor(av[e], 1); av[e] += __shfl_xor(av[e], 2); av[e] += __shfl_xor(av[e], 4);
        }
        const size_t kvb = ((size_t)l * NB) * T_ * D_ + (size_t)i * D_ + og;
        if (k8 < 4) {
          const int e = k8;
          qb[e][og] = SEL4(aq, e) + bqkv[l * 384 + og];
          Vc[kvb + (size_t)e * T_ * D_] = SEL4(av, e) + bqkv[l * 384 + 256 + og];
        } else {
          const int e = k8 - 4;
          Kc[kvb + (size_t)e * T_ * D_] = SEL4(ak, e) + bqkv[l * 384 + 128 + og];
        }
      }
      __syncthreads();

      // ======== phase: attention (+ prefetch all wo weights) ========
      const float* worow = wo + ((size_t)l * D_ + og) * D_;
      const float4 po0 = ld4(worow + 4 * k8);
      const float4 po1 = ld4(worow + 4 * (k8 + 8));
      const float4 po2 = ld4(worow + 4 * (k8 + 16));
      const float4 po3 = ld4(worow + 4 * (k8 + 24));
      {
        const int e = w >> 2, h = w & 3;
        // scores: lane = t, causal-guarded loads
        const int t = lane;
        float s0 = -INFINITY;
        if (t <= i) {
          const float4* q4 = reinterpret_cast<const float4*>(&qb[e][h * DH_]);
          const float* kp = Kc + (((size_t)l * NB + e) * T_ + t) * D_ + h * DH_;
          float a = 0.f;
#pragma unroll
          for (int k = 0; k < 8; ++k) {
            const float4 qv = q4[k];
            const float4 kv = ld4(kp + 4 * k);
            a += qv.x * kv.x + qv.y * kv.y + qv.z * kv.z + qv.w * kv.w;
          }
          s0 = a * 0.17677669529663687f;
        }
        float mx = s0;
#pragma unroll
        for (int off = 32; off > 0; off >>= 1) mx = fmaxf(mx, __shfl_xor(mx, off));
        float p = expf(s0 - mx);                 // 0 for t>i
        float sum = p;
#pragma unroll
        for (int off = 32; off > 0; off >>= 1) sum += __shfl_xor(sum, off);
        sc[e][h][t] = p / sum;

        // PV: lane = (thalf, j); causal-guarded loads
        const int j = lane & 31, thalf = lane >> 5;
        const float* vp = Vc + (((size_t)l * NB + e) * T_ + thalf * 32) * D_ + h * DH_ + j;
        const float* pp = &sc[e][h][thalf * 32];
        float acc = 0.f;
#pragma unroll
        for (int m2 = 0; m2 < 32; ++m2) {
          if (thalf * 32 + m2 <= i) acc += pp[m2] * vp[(size_t)m2 * D_];
        }
        acc += __shfl_xor(acc, 32);
        if (thalf == 0) qb[e][h * DH_ + j] = acc;
      }
      __syncthreads();

      // ======== phase: wo (+ prefetch FFN1 weights m=0,1) ========
      const float* w1b = w1 + ((size_t)l * DFF_ + og) * D_;
      const float4 pf00 = ld4(w1b + 4 * k8);
      const float4 pf10 = ld4(w1b + (size_t)128 * D_ + 4 * k8);
      const float4 pf20 = ld4(w1b + (size_t)256 * D_ + 4 * k8);
      const float4 pf30 = ld4(w1b + (size_t)384 * D_ + 4 * k8);
      const float4 pf01 = ld4(w1b + 4 * (k8 + 8));
      const float4 pf11 = ld4(w1b + (size_t)128 * D_ + 4 * (k8 + 8));
      const float4 pf21 = ld4(w1b + (size_t)256 * D_ + 4 * (k8 + 8));
      const float4 pf31 = ld4(w1b + (size_t)384 * D_ + 4 * (k8 + 8));
      {
        float ac[4] = {0.f, 0.f, 0.f, 0.f};
#pragma unroll
        for (int e = 0; e < 4; ++e) {
          DOT4(ac[e], po0, &qb[e][4 * k8]);
          DOT4(ac[e], po1, &qb[e][4 * (k8 + 8)]);
          DOT4(ac[e], po2, &qb[e][4 * (k8 + 16)]);
          DOT4(ac[e], po3, &qb[e][4 * (k8 + 24)]);
        }
#pragma unroll
        for (int e = 0; e < 4; ++e) {
          ac[e] += __shfl_xor(ac[e], 1); ac[e] += __shfl_xor(ac[e], 2); ac[e] += __shfl_xor(ac[e], 4);
        }
        if (k8 < 4) {
          const int e = k8;
          xres[e][og] += SEL4(ac, e) + bo[l * D_ + og];
        }
      }
      __syncthreads();

      // ======== phase: LN2 ========
      if (w < NB) ln_wave(xres[w], xn[w], ln2w + l * D_, ln2b + l * D_, lane);
      __syncthreads();

      // ======== phase: FFN1 + GELU (+ prefetch FFN2 weights m=0..3) ========
      const float* w2row = w2 + ((size_t)l * D_ + og) * DFF_;
      const float4 pg0 = ld4(w2row + 4 * k8);
      const float4 pg1 = ld4(w2row + 4 * (k8 + 8));
      const float4 pg2 = ld4(w2row + 4 * (k8 + 16));
      const float4 pg3 = ld4(w2row + 4 * (k8 + 24));
      {
        float ac[4][4];
#pragma unroll
        for (int r = 0; r < 4; ++r)
#pragma unroll
          for (int e = 0; e < 4; ++e) ac[r][e] = 0.f;
#pragma unroll
        for (int e = 0; e < 4; ++e) {
          DOT4(ac[0][e], pf00, &xn[e][4 * k8]);
          DOT4(ac[1][e], pf10, &xn[e][4 * k8]);
          DOT4(ac[2][e], pf20, &xn[e][4 * k8]);
          DOT4(ac[3][e], pf30, &xn[e][4 * k8]);
          DOT4(ac[0][e], pf01, &xn[e][4 * (k8 + 8)]);
          DOT4(ac[1][e], pf11, &xn[e][4 * (k8 + 8)]);
          DOT4(ac[2][e], pf21, &xn[e][4 * (k8 + 8)]);
          DOT4(ac[3][e], pf31, &xn[e][4 * (k8 + 8)]);
        }
#pragma unroll
        for (int m = 2; m < 4; ++m) {
          const int f4 = k8 + 8 * m;
          float4 wr[4];
#pragma unroll
          for (int r = 0; r < 4; ++r) wr[r] = ld4(w1b + (size_t)(128 * r) * D_ + 4 * f4);
#pragma unroll
          for (int e = 0; e < 4; ++e) {
            const float4 x4 = ld4(&xn[e][4 * f4]);
#pragma unroll
            for (int r = 0; r < 4; ++r) {
              ac[r][e] += wr[r].x * x4.x + wr[r].y * x4.y + wr[r].z * x4.z + wr[r].w * x4.w;
            }
          }
        }
#pragma unroll
        for (int r = 0; r < 4; ++r)
#pragma unroll
          for (int e = 0; e < 4; ++e) {
            ac[r][e] += __shfl_xor(ac[r][e], 1);
            ac[r][e] += __shfl_xor(ac[r][e], 2);
            ac[r][e] += __shfl_xor(ac[r][e], 4);
          }
        if (k8 < 4) {
          const int e = k8;
          hbuf[e][og] = gelu_exact(SEL4(ac[0], e) + b1[l * DFF_ + og]);
          hbuf[e][og + 128] = gelu_exact(SEL4(ac[1], e) + b1[l * DFF_ + og + 128]);
        } else {
          const int e = k8 - 4;
          hbuf[e][og + 256] = gelu_exact(SEL4(ac[2], e) + b1[l * DFF_ + og + 256]);
          hbuf[e][og + 384] = gelu_exact(SEL4(ac[3], e) + b1[l * DFF_ + og + 384]);
        }
      }
      __syncthreads();

      // ======== phase: FFN2 ========
      {
        float ac[4] = {0.f, 0.f, 0.f, 0.f};
#pragma unroll
        for (int e = 0; e < 4; ++e) {
          DOT4(ac[e], pg0, &hbuf[e][4 * k8]);
          DOT4(ac[e], pg1, &hbuf[e][4 * (k8 + 8)]);
          DOT4(ac[e], pg2, &hbuf[e][4 * (k8 + 16)]);
          DOT4(ac[e], pg3, &hbuf[e][4 * (k8 + 24)]);
        }
#pragma unroll
        for (int m = 4; m < 16; ++m) {
          const int f4 = k8 + 8 * m;
          const float4 w4 = ld4(w2row + 4 * f4);
#pragma unroll
          for (int e = 0; e < 4; ++e) {
            DOT4(ac[e], w4, &hbuf[e][4 * f4]);
          }
        }
#pragma unroll
        for (int e = 0; e < 4; ++e) {
          ac[e] += __shfl_xor(ac[e], 1); ac[e] += __shfl_xor(ac[e], 2); ac[e] += __shfl_xor(ac[e], 4);
        }
        if (k8 < 4) {
          const int e = k8;
          xres[e][og] += SEL4(ac, e) + b2[l * D_ + og];
        }
      }
      __syncthreads();
    }  // layers

    // ---- final LN
    if (w < NB) ln_wave(xres[w], xn[w], fnw, fnb, lane);
    __syncthreads();

    // ---- head: 512 threads: (e, s, j)
    if (tid < 512) {
      const int e = tid >> 7, rest = tid & 127, s = rest >> 5, j = rest & 31;
      const float4 a = ld4(&xn[e][4 * j]);
      const float4 hw = ld4(headw + s * D_ + 4 * j);
      float acc = a.x * hw.x + a.y * hw.y + a.z * hw.z + a.w * hw.w;
#pragma unroll
      for (int off = 1; off < 32; off <<= 1) acc += __shfl_xor(acc, off);
      if (j == 0) logits[e][s] = acc + headb[s];
    }
    __syncthreads();

    // ---- mask + log-softmax + gumbel-argmax (threads 0..3)
    if (tid < NB) {
      const int e = tid;
      const int b = blk * NB + e;
      const int a = arem_r, bb = brem_r;
      const int oa = T_ - 1 - i;
      bool m[4];
      m[0] = (a <= oa) && (bb <= oa);
      m[1] = (bb > 0) && (a <= oa) && (bb - 1 <= oa);
      m[2] = (a > 0) && (a - 1 <= oa) && (bb <= oa);
      m[3] = (a > 0) && (bb > 0) && (a - 1 <= oa) && (bb - 1 <= oa);
      float mx = -INFINITY;
#pragma unroll
      for (int s = 0; s < 4; ++s)
        if (m[s]) mx = fmaxf(mx, logits[e][s]);
      float sum = 0.f;
      float lg[4];
#pragma unroll
      for (int s = 0; s < 4; ++s) {
        if (m[s]) {
          const float z = logits[e][s] - mx;
          sum += expf(z);
          lg[s] = z;
        } else {
          lg[s] = -INFINITY;
        }
      }
      const float lse = logf(sum);
      float best = -INFINITY;
      int bs = 0;
#pragma unroll
      for (int s = 0; s < 4; ++s) {
        const float lp = lg[s] - lse;
        const float y = lp + gumbel[((size_t)b * T_ + i) * S_ + s];
        if (y > best) { best = y; bs = s; }
      }
      lps_r += SEL4(lg, bs) - lse;
      out[(size_t)b * T_ + i] = (float)bs;
      tok[e] = bs;
      arem_r = a - (bs >> 1);
      brem_r = bb - (bs & 1);
    }
    __syncthreads();
  }  // steps

  if (tid < NB) out[(size_t)B_ * T_ + blk * NB + tid] = lps_r;
}

extern "C" void kernel_launch(void* const* d_in, const int* in_sizes, int n_in,
                              void* d_out, int out_size, void* d_ws, size_t ws_size,
                              hipStream_t stream) {
  const float* gumbel    = (const float*)d_in[0];
  const float* state_emb = (const float*)d_in[1];
  const float* pos_emb   = (const float*)d_in[2];
  const float* ln1w      = (const float*)d_in[3];
  const float* ln1b      = (const float*)d_in[4];
  const float* wqkv      = (const float*)d_in[5];
  const float* bqkv      = (const float*)d_in[6];
  const float* wo        = (const float*)d_in[7];
  const float* bo        = (const float*)d_in[8];
  const float* ln2w      = (const float*)d_in[9];
  const float* ln2b      = (const float*)d_in[10];
  const float* w1        = (const float*)d_in[11];
  const float* b1        = (const float*)d_in[12];
  const float* w2        = (const float*)d_in[13];
  const float* b2        = (const float*)d_in[14];
  const float* fnw       = (const float*)d_in[15];
  const float* fnb       = (const float*)d_in[16];
  const float* headw     = (const float*)d_in[17];
  const float* headb     = (const float*)d_in[18];
  const int* nalpha      = (const int*)d_in[19];
  const int* nbeta       = (const int*)d_in[20];
  float* ws = (float*)d_ws;
  float* out = (float*)d_out;

  decode_kernel<<<dim3(NBLK), dim3(NTH), 0, stream>>>(
      gumbel, state_emb, pos_emb, ln1w, ln1b, wqkv, bqkv, wo, bo, ln2w, ln2b,
      w1, b1, w2, b2, fnw, fnb, headw, headb, nalpha, nbeta, ws, out);
}